// Round 5
// baseline (119.899 us; speedup 1.0000x reference)
//
#include <hip/hip_runtime.h>

// Sinkhorn (loop-never-runs degenerate): out[b] = sum_{i,j} c * exp(-10*c),
// c = (xs_i - ys_j)^2 + (x_i - y_j)^2.  B=8, N=M=4096.
//
// MFMA formulation: u = K*c is a rank-4 outer product,
//   u[i][j] = Ka_i*1 + 1*Kb_j + (m2K*xs_i)*ys_j + (m2K*x_i)*y_j
// so a 16x16 tile of u is ONE v_mfma_f32_16x16x16f16 (K=4 used, rest zero).
// Then sum c*e^{-10c} = (1/K) * sum u*2^u: per 256 pairs only 4 exp + 4 fma
// per lane. A/B fragments are pre-baked lane-indexed (zero-padded) into d_ws
// by a prep kernel, so the hot loop is: 8B coalesced load + mfma + epilogue.
// Robustness: we only SUM all tile elements -> C/D layout irrelevant; A and B
// operands share the same quad-k mapping, so k-pairing is correct by
// construction.

typedef _Float16 half4 __attribute__((ext_vector_type(4)));
typedef float float4v __attribute__((ext_vector_type(4)));

constexpr int B_ = 8;
constexpr int NN = 4096;
constexpr int NT = 256;                    // 16-row/col tiles per dim
constexpr float K_   = -14.426950408889634f;   // -10 * log2(e)
constexpr float m2K_ =  28.853900817779268f;   // -2 * K

// ws layout: Af[(b*NT + tile)*64 + lane] (1 MB), then Bf same shape (1 MB).
constexpr size_t FRAG_ELEMS = (size_t)B_ * NT * 64;

__global__ __launch_bounds__(256) void prep_kernel(
    const float* __restrict__ x,  const float* __restrict__ y,
    const float* __restrict__ xs, const float* __restrict__ ys,
    half4* __restrict__ Af, half4* __restrict__ Bf)
{
    const int gid  = blockIdx.x * 256 + threadIdx.x;  // 0 .. 131071
    const int lane = gid & 63;
    const int tile = (gid >> 6) & (NT - 1);
    const int b    = gid >> 14;

    half4 av = {0, 0, 0, 0};
    half4 bv = {0, 0, 0, 0};
    if (lane < 16) {                       // k rows 0..3 live in lanes 0..15
        const int i = tile * 16 + lane;
        const float sxi = xs[b * NN + i], vxi = x[b * NN + i];
        const float syj = ys[b * NN + i], vyj = y[b * NN + i];
        const float Ka = K_ * (sxi * sxi + vxi * vxi);
        const float Kb = K_ * (syj * syj + vyj * vyj);
        av = half4{(_Float16)Ka, (_Float16)1.0f,
                   (_Float16)(m2K_ * sxi), (_Float16)(m2K_ * vxi)};
        bv = half4{(_Float16)1.0f, (_Float16)Kb,
                   (_Float16)syj, (_Float16)vyj};
    }
    Af[gid] = av;
    Bf[gid] = bv;
}

// Grid: 8 batches x 256 col-tiles x 2 row-halves = 4096 blocks, 4 waves each.
// Wave w handles row-tiles [h*128 + w*32, +32) for its block's col-tile.
__global__ __launch_bounds__(256, 8) void sinkhorn_mfma(
    const half4* __restrict__ Af, const half4* __restrict__ Bf,
    float* __restrict__ out)
{
    const int b    = blockIdx.x >> 9;
    const int rem  = blockIdx.x & 511;
    const int ct   = rem >> 1;
    const int h    = rem & 1;
    const int t    = threadIdx.x;
    const int wave = t >> 6;
    const int lane = t & 63;

    const half4 bfrag = Bf[((b << 8) + ct) * 64 + lane];

    const int rt0 = (h << 7) + wave * 32;
    const half4* ap = Af + ((size_t)(b << 8) + rt0) * 64 + lane;

    float4v acc = {0, 0, 0, 0};
    half4 a_cur = *ap;
#pragma unroll 4
    for (int i = 0; i < 32; ++i) {
        ap += 64;
        half4 a_nxt = *ap;   // final iter overreads into Bf region (in ws), unused
        float4v d = __builtin_amdgcn_mfma_f32_16x16x16f16(
            a_cur, bfrag, (float4v){0, 0, 0, 0}, 0, 0, 0);
        const float e0 = __builtin_amdgcn_exp2f(d.x);
        const float e1 = __builtin_amdgcn_exp2f(d.y);
        const float e2 = __builtin_amdgcn_exp2f(d.z);
        const float e3 = __builtin_amdgcn_exp2f(d.w);
        acc.x += d.x * e0;
        acc.y += d.y * e1;
        acc.z += d.z * e2;
        acc.w += d.w * e3;
        a_cur = a_nxt;
    }

    float a = (acc.x + acc.y + acc.z + acc.w) * (1.0f / K_);

#pragma unroll
    for (int off = 32; off > 0; off >>= 1)
        a += __shfl_down(a, off, 64);

    __shared__ float wsum[4];
    if (lane == 0) wsum[wave] = a;
    __syncthreads();
    if (t == 0)
        atomicAdd(&out[b], wsum[0] + wsum[1] + wsum[2] + wsum[3]);
}

extern "C" void kernel_launch(void* const* d_in, const int* in_sizes, int n_in,
                              void* d_out, int out_size, void* d_ws, size_t ws_size,
                              hipStream_t stream) {
    const float* x  = (const float*)d_in[0];
    const float* y  = (const float*)d_in[1];
    const float* xs = (const float*)d_in[2];
    const float* ys = (const float*)d_in[3];
    float* out = (float*)d_out;

    half4* Af = (half4*)d_ws;
    half4* Bf = Af + FRAG_ELEMS;

    // d_out is poisoned 0xAA before every launch — zero it (capture-safe).
    hipMemsetAsync(out, 0, (size_t)out_size * sizeof(float), stream);

    prep_kernel<<<(B_ * NT * 64) / 256, 256, 0, stream>>>(x, y, xs, ys, Af, Bf);
    sinkhorn_mfma<<<B_ * NT * 2, 256, 0, stream>>>(Af, Bf, out);
}

// Round 6
// 92.860 us; speedup vs baseline: 1.2912x; 1.2912x over previous
//
#include <hip/hip_runtime.h>

// Sinkhorn (loop-never-runs degenerate): out[b] = sum_{i,j} c * exp(-10*c),
// c = (xs_i - ys_j)^2 + (x_i - y_j)^2.  B=8, N=M=4096.
//
// Rank-4 MFMA formulation, 32x32 tiles:
//   u[i][j] = K*c = Ka_i*1 + 1*Kb_j + (m2K*xs_i)*ys_j + (m2K*x_i)*y_j
// One v_mfma_f32_32x32x8f16 = 1024 pairs; epilogue = 16 INDEPENDENT
// exp+fma per lane (R5's 16x16 version had ILP=4 and stalled at 17% busy).
// A/B frags pre-baked lane-indexed; lanes 0..31 carry k=0..3, lanes 32..63
// zero — A and B share the lane->k mapping so pairing is correct under any
// (consistent) HW mapping; C/D layout irrelevant (we sum the whole tile).

typedef _Float16 half4 __attribute__((ext_vector_type(4)));
typedef float f32x16 __attribute__((ext_vector_type(16)));

constexpr int B_ = 8;
constexpr int NN = 4096;
constexpr int NT = 128;                        // 32-wide tiles per dim
constexpr float K_   = -14.426950408889634f;   // -10 * log2(e)
constexpr float m2K_ =  28.853900817779268f;   // -2 * K

// ws: Af[(b*NT + tile)*64 + lane] (512 KB), Bf same (512 KB).
constexpr size_t FRAG_ELEMS = (size_t)B_ * NT * 64;

__global__ __launch_bounds__(256) void prep_kernel(
    const float* __restrict__ x,  const float* __restrict__ y,
    const float* __restrict__ xs, const float* __restrict__ ys,
    half4* __restrict__ Af, half4* __restrict__ Bf)
{
    const int gid  = blockIdx.x * 256 + threadIdx.x;  // 0 .. 65535
    const int lane = gid & 63;
    const int tile = (gid >> 6) & (NT - 1);
    const int b    = gid >> 13;

    half4 av = {0, 0, 0, 0};
    half4 bv = {0, 0, 0, 0};
    if (lane < 32) {                  // k=0..3 lives in lanes 0..31
        const int i = tile * 32 + lane;
        const float sxi = xs[b * NN + i], vxi = x[b * NN + i];
        const float syj = ys[b * NN + i], vyj = y[b * NN + i];
        const float Ka = K_ * (sxi * sxi + vxi * vxi);
        const float Kb = K_ * (syj * syj + vyj * vyj);
        av = half4{(_Float16)Ka, (_Float16)1.0f,
                   (_Float16)(m2K_ * sxi), (_Float16)(m2K_ * vxi)};
        bv = half4{(_Float16)1.0f, (_Float16)Kb,
                   (_Float16)syj, (_Float16)vyj};
    }
    Af[gid] = av;
    Bf[gid] = bv;
}

// Grid: 8 b x 128 col-tiles x 2 halves = 2048 blocks x 4 waves.
// Wave w of half h handles row-tiles [(h*4+w)*16, +16).
__global__ __launch_bounds__(256, 6) void sinkhorn_mfma(
    const half4* __restrict__ Af, const half4* __restrict__ Bf,
    float* __restrict__ out)
{
    const int b    = blockIdx.x >> 8;
    const int rem  = blockIdx.x & 255;
    const int ct   = rem >> 1;
    const int h    = rem & 1;
    const int t    = threadIdx.x;
    const int wave = t >> 6;
    const int lane = t & 63;

    const half4 bfrag = Bf[((b << 7) + ct) * 64 + lane];

    const int chunk = (h << 2) + wave;                 // 0..7
    const half4* ap = Af + ((size_t)((b << 7) + (chunk << 4))) * 64 + lane;

    f32x16 acc = {};
    half4 a0 = ap[0];
    half4 a1 = ap[64];
#pragma unroll 2
    for (int i = 0; i < 16; ++i) {
        const half4 a_use = a0;
        a0 = a1;
        a1 = ap[(i + 2) * 64];   // last 2 iters overread into Bf region (unused)
        f32x16 d = __builtin_amdgcn_mfma_f32_32x32x8f16(
            a_use, bfrag, (f32x16){}, 0, 0, 0);
#pragma unroll
        for (int r = 0; r < 16; ++r) {
            const float e = __builtin_amdgcn_exp2f(d[r]);
            acc[r] += d[r] * e;    // 16 independent chains
        }
    }

    float a = 0.0f;
#pragma unroll
    for (int r = 0; r < 16; ++r) a += acc[r];
    a *= (1.0f / K_);

#pragma unroll
    for (int off = 32; off > 0; off >>= 1)
        a += __shfl_down(a, off, 64);

    __shared__ float wsum[4];
    if (lane == 0) wsum[wave] = a;
    __syncthreads();
    if (t == 0)
        atomicAdd(&out[b], wsum[0] + wsum[1] + wsum[2] + wsum[3]);
}

extern "C" void kernel_launch(void* const* d_in, const int* in_sizes, int n_in,
                              void* d_out, int out_size, void* d_ws, size_t ws_size,
                              hipStream_t stream) {
    const float* x  = (const float*)d_in[0];
    const float* y  = (const float*)d_in[1];
    const float* xs = (const float*)d_in[2];
    const float* ys = (const float*)d_in[3];
    float* out = (float*)d_out;

    half4* Af = (half4*)d_ws;
    half4* Bf = Af + FRAG_ELEMS;

    // d_out is poisoned 0xAA before every launch — zero it (capture-safe).
    hipMemsetAsync(out, 0, (size_t)out_size * sizeof(float), stream);

    prep_kernel<<<(B_ * NT * 64) / 256, 256, 0, stream>>>(x, y, xs, ys, Af, Bf);
    sinkhorn_mfma<<<B_ * NT * 2, 256, 0, stream>>>(Af, Bf, out);
}

// Round 7
// 90.240 us; speedup vs baseline: 1.3287x; 1.0290x over previous
//
#include <hip/hip_runtime.h>

// Sinkhorn (loop-never-runs degenerate): out[b] = sum_{i,j} c * exp(-10*c),
// c = (xs_i - ys_j)^2 + (x_i - y_j)^2.  B=8, N=M=4096.
//
// Rank-4 MFMA formulation, 32x32 tiles, FUSED (no prep kernel):
//   u[i][j] = K*c = Ka_i*1 + 1*Kb_j + (m2K*xs_i)*ys_j + (m2K*x_i)*y_j
// Fragments built in-register from raw floats. Each wave runs TWO independent
// mfma tiles per step (2 load chains + 2 mfmas + 32 independent exp/fma) with
// a distance-1 software pipeline on the x-loads — R2/R4/R6 all pinned at
// ~32 us (4-6x their issue floors) because every version had a depth-1
// load->mfma->epilogue chain; this doubles the independent work in flight.
// Lanes 0..31 carry k=0..3 for both A and B (lanes 32..63 masked to zero), so
// the k-pairing is correct under the HW mapping (validated R5/R6: absmax 0.0);
// C/D layout irrelevant (we sum the whole tile).

typedef _Float16 half4 __attribute__((ext_vector_type(4)));
typedef float f32x16 __attribute__((ext_vector_type(16)));

constexpr int B_ = 8;
constexpr int NN = 4096;
constexpr float K_   = -14.426950408889634f;   // -10 * log2(e)
constexpr float m2K_ =  28.853900817779268f;   // -2 * K

// Grid: 8 batches x 128 col-tiles x 2 halves = 2048 blocks x 256 thr.
// Wave w of half h: 16 row-tiles starting at (h*4+w)*16, two per step.
__global__ __launch_bounds__(256, 4) void sinkhorn_fused(
    const float* __restrict__ x,  const float* __restrict__ y,
    const float* __restrict__ xs, const float* __restrict__ ys,
    float* __restrict__ out)
{
    const int b    = blockIdx.x >> 8;
    const int rem  = blockIdx.x & 255;
    const int ct   = rem >> 1;
    const int h    = rem & 1;
    const int t    = threadIdx.x;
    const int wave = t >> 6;
    const int lane = t & 63;
    const int l31  = lane & 31;
    const float maskf = (lane < 32) ? 1.0f : 0.0f;  // k=0..3 lives in lanes 0..31

    const float* xb  = x  + (size_t)b * NN;
    const float* yb  = y  + (size_t)b * NN;
    const float* xsb = xs + (size_t)b * NN;
    const float* ysb = ys + (size_t)b * NN;

    // B fragment for col-tile ct (built once).
    const int j = ct * 32 + l31;
    const float syj = ysb[j] * maskf;
    const float vyj = yb[j]  * maskf;
    const half4 bfrag = { (_Float16)maskf,
                          (_Float16)(K_ * (syj * syj + vyj * vyj)),
                          (_Float16)syj, (_Float16)vyj };

    const int tile0 = (h * 4 + wave) * 16;
    const int r0    = tile0 * 32 + l31;

    // distance-1 pipeline on the two row-tile load chains
    float sx0 = xsb[r0],      vx0 = xb[r0];
    float sx1 = xsb[r0 + 32], vx1 = xb[r0 + 32];

    f32x16 acc0 = {}, acc1 = {};
#pragma unroll
    for (int s = 0; s < 8; ++s) {
        const float msx0 = sx0 * maskf, mvx0 = vx0 * maskf;
        const float msx1 = sx1 * maskf, mvx1 = vx1 * maskf;
        const half4 a0 = { (_Float16)(K_ * (msx0 * msx0 + mvx0 * mvx0)),
                           (_Float16)maskf,
                           (_Float16)(m2K_ * msx0), (_Float16)(m2K_ * mvx0) };
        const half4 a1 = { (_Float16)(K_ * (msx1 * msx1 + mvx1 * mvx1)),
                           (_Float16)maskf,
                           (_Float16)(m2K_ * msx1), (_Float16)(m2K_ * mvx1) };
        if (s < 7) {   // compile-time guard (loop fully unrolled)
            const int rn = r0 + (s + 1) * 64;
            sx0 = xsb[rn];      vx0 = xb[rn];
            sx1 = xsb[rn + 32]; vx1 = xb[rn + 32];
        }
        f32x16 d0 = __builtin_amdgcn_mfma_f32_32x32x8f16(a0, bfrag, (f32x16){}, 0, 0, 0);
        f32x16 d1 = __builtin_amdgcn_mfma_f32_32x32x8f16(a1, bfrag, (f32x16){}, 0, 0, 0);
#pragma unroll
        for (int r = 0; r < 16; ++r) {
            acc0[r] += d0[r] * __builtin_amdgcn_exp2f(d0[r]);
            acc1[r] += d1[r] * __builtin_amdgcn_exp2f(d1[r]);
        }
    }

    float a = 0.0f;
#pragma unroll
    for (int r = 0; r < 16; ++r) a += acc0[r] + acc1[r];
    a *= (1.0f / K_);

#pragma unroll
    for (int off = 32; off > 0; off >>= 1)
        a += __shfl_down(a, off, 64);

    __shared__ float wsum[4];
    if (lane == 0) wsum[wave] = a;
    __syncthreads();
    if (t == 0)
        atomicAdd(&out[b], wsum[0] + wsum[1] + wsum[2] + wsum[3]);
}

extern "C" void kernel_launch(void* const* d_in, const int* in_sizes, int n_in,
                              void* d_out, int out_size, void* d_ws, size_t ws_size,
                              hipStream_t stream) {
    const float* x  = (const float*)d_in[0];
    const float* y  = (const float*)d_in[1];
    const float* xs = (const float*)d_in[2];
    const float* ys = (const float*)d_in[3];
    float* out = (float*)d_out;

    // d_out is poisoned 0xAA before every launch — zero it (capture-safe).
    hipMemsetAsync(out, 0, (size_t)out_size * sizeof(float), stream);

    sinkhorn_fused<<<B_ * 128 * 2, 256, 0, stream>>>(x, y, xs, ys, out);
}